// Round 1
// baseline (480.719 us; speedup 1.0000x reference)
//
#include <hip/hip_runtime.h>

#define NN 512
#define CCH 128
#define MM (NN*NN)   // 262144

using f32x4  = __attribute__((ext_vector_type(4))) float;
using f32x2  = __attribute__((ext_vector_type(2))) float;
using bf16x8 = __attribute__((ext_vector_type(8))) short;
using u32x2  = __attribute__((ext_vector_type(2))) unsigned int;
typedef unsigned short u16;

__device__ __forceinline__ u16 f2bf(float f) {
    unsigned u = __builtin_bit_cast(unsigned, f);
    u += 0x7FFF + ((u >> 16) & 1);
    return (u16)(u >> 16);
}
__device__ __forceinline__ float bf2f(u16 h) {
    unsigned u = ((unsigned)h) << 16;
    return __builtin_bit_cast(float, u);
}
__device__ __forceinline__ float sigm(float x) { return 1.0f / (1.0f + __expf(-x)); }

__device__ __forceinline__ void gl_lds16(const void* g, void* l) {
    __builtin_amdgcn_global_load_lds(
        (const __attribute__((address_space(1))) void*)g,
        (__attribute__((address_space(3))) void*)l, 16, 0, 0);
}

// ---------------- Kernel 1: LayerNorm(z) -> zn (bf16) ----------------
__global__ __launch_bounds__(256) void k_ln_in(const float* __restrict__ z,
                                               const float* __restrict__ g,
                                               const float* __restrict__ b,
                                               u16* __restrict__ zn) {
    int tid = threadIdx.x;
    int w = tid >> 6, lane = tid & 63;
    long row = (long)blockIdx.x * 4 + w;
    const float* zr = z + row * CCH;
    f32x2 v = *(const f32x2*)(zr + lane * 2);
    float s = v.x + v.y, s2 = v.x * v.x + v.y * v.y;
    #pragma unroll
    for (int off = 32; off; off >>= 1) {
        s  += __shfl_xor(s, off);
        s2 += __shfl_xor(s2, off);
    }
    float mu  = s * (1.0f / CCH);
    float var = s2 * (1.0f / CCH) - mu * mu;
    float rs  = rsqrtf(var + 1e-5f);
    int c = lane * 2;
    float o0 = (v.x - mu) * rs * g[c]     + b[c];
    float o1 = (v.y - mu) * rs * g[c + 1] + b[c + 1];
    unsigned pk = (unsigned)f2bf(o0) | ((unsigned)f2bf(o1) << 16);
    *(unsigned*)(zn + row * CCH + c) = pk;
}

// ---------------- Kernel 2: projections ----------------
// MODE 0: out_t[c][m] = mask[m]*sigmoid(zn@W1^T+B1)*(zn@W2^T+B2)   (transposed bf16)
// MODE 1: out[m][c]   = sigmoid(zn@W1^T+B1)                        (row-major bf16)
template <int MODE>
__global__ __launch_bounds__(256) void k_proj(const u16* __restrict__ zn,
                                              const float* __restrict__ mask,
                                              const float* __restrict__ W1,
                                              const float* __restrict__ B1,
                                              const float* __restrict__ W2,
                                              const float* __restrict__ B2,
                                              u16* __restrict__ out) {
    __shared__ u16 w1s[16384];   // [128][128] bf16, swizzled
    __shared__ u16 w2s[16384];
    u16* tb = w1s;               // 16KB transpose buffer, aliases w1s (post-MFMA)

    int tid  = threadIdx.x;
    int w    = tid >> 6, lane = tid & 63;
    int m0   = blockIdx.x * 64;
    int r    = lane & 15, kq = lane >> 4;

    // stage weights (f32 -> bf16, XOR swizzle on 16B within 256B row)
    {
        int n = tid >> 1, kb = (tid & 1) * 64;
        int sw = (n & 7) << 4;
        #pragma unroll
        for (int q = 0; q < 16; ++q) {
            int k = kb + q * 4;
            f32x4 wv = *(const f32x4*)(W1 + n * CCH + k);
            u32x2 pk;
            pk.x = (unsigned)f2bf(wv.x) | ((unsigned)f2bf(wv.y) << 16);
            pk.y = (unsigned)f2bf(wv.z) | ((unsigned)f2bf(wv.w) << 16);
            *(u32x2*)((char*)w1s + n * 256 + ((2 * k) ^ sw)) = pk;
            if (MODE == 0) {
                f32x4 wv2 = *(const f32x4*)(W2 + n * CCH + k);
                u32x2 pk2;
                pk2.x = (unsigned)f2bf(wv2.x) | ((unsigned)f2bf(wv2.y) << 16);
                pk2.y = (unsigned)f2bf(wv2.z) | ((unsigned)f2bf(wv2.w) << 16);
                *(u32x2*)((char*)w2s + n * 256 + ((2 * k) ^ sw)) = pk2;
            }
        }
    }

    // A fragments straight from global (rows of zn)
    long mrow = (long)m0 + w * 16 + r;
    bf16x8 av[4];
    #pragma unroll
    for (int kb = 0; kb < 4; ++kb)
        av[kb] = *(const bf16x8*)(zn + mrow * CCH + kb * 32 + kq * 8);

    __syncthreads();

    f32x4 acc1[8], acc2[8];
    #pragma unroll
    for (int nt = 0; nt < 8; ++nt) { acc1[nt] = {0.f,0.f,0.f,0.f}; acc2[nt] = {0.f,0.f,0.f,0.f}; }

    #pragma unroll
    for (int nt = 0; nt < 8; ++nt) {
        int nrow = nt * 16 + r;
        int rb = nrow * 256, sw = (nrow & 7) << 4;
        #pragma unroll
        for (int kb = 0; kb < 4; ++kb) {
            bf16x8 bf = *(const bf16x8*)((const char*)w1s + rb + ((kb * 64 + kq * 16) ^ sw));
            acc1[nt] = __builtin_amdgcn_mfma_f32_16x16x32_bf16(av[kb], bf, acc1[nt], 0, 0, 0);
        }
        if (MODE == 0) {
            #pragma unroll
            for (int kb = 0; kb < 4; ++kb) {
                bf16x8 bf = *(const bf16x8*)((const char*)w2s + rb + ((kb * 64 + kq * 16) ^ sw));
                acc2[nt] = __builtin_amdgcn_mfma_f32_16x16x32_bf16(av[kb], bf, acc2[nt], 0, 0, 0);
            }
        }
    }

    float mk[4];
    if (MODE == 0) {
        #pragma unroll
        for (int j = 0; j < 4; ++j) mk[j] = mask[m0 + w * 16 + kq * 4 + j];
    }

    __syncthreads();   // w1s/w2s reads done; tb (alias of w1s) now writable

    if (MODE == 0) {
        #pragma unroll
        for (int nt = 0; nt < 8; ++nt) {
            int cc = nt * 16 + r;
            float b1v = B1[cc], b2v = B2[cc];
            int swc = (cc & 7) << 4;
            #pragma unroll
            for (int j = 0; j < 4; ++j) {
                int ml = w * 16 + kq * 4 + j;
                float val = mk[j] * sigm(acc1[nt][j] + b1v) * (acc2[nt][j] + b2v);
                *(u16*)((char*)tb + cc * 128 + ((ml * 2) ^ swc)) = f2bf(val);
            }
        }
        __syncthreads();
        int c = tid >> 1, half = tid & 1;
        long gbase = (long)c * MM + m0 + half * 32;
        int sw = (c & 7) << 4;
        #pragma unroll
        for (int qq = 0; qq < 4; ++qq) {
            bf16x8 vv = *(const bf16x8*)((const char*)tb + c * 128 + ((half * 64 + qq * 16) ^ sw));
            *(bf16x8*)(out + gbase + qq * 8) = vv;
        }
    } else {
        #pragma unroll
        for (int nt = 0; nt < 8; ++nt) {
            int cc = nt * 16 + r;
            float b1v = B1[cc];
            #pragma unroll
            for (int j = 0; j < 4; ++j) {
                int ml = w * 16 + kq * 4 + j;
                float val = sigm(acc1[nt][j] + b1v);
                *(u16*)((char*)tb + ml * 256 + ((cc * 2) ^ ((ml & 7) << 4))) = f2bf(val);
            }
        }
        __syncthreads();
        int ml = tid >> 2, q4 = tid & 3;
        long gbase = (long)(m0 + ml) * CCH + q4 * 32;
        int sw = (ml & 7) << 4;
        #pragma unroll
        for (int qq = 0; qq < 4; ++qq) {
            bf16x8 vv = *(const bf16x8*)((const char*)tb + ml * 256 + ((q4 * 64 + qq * 16) ^ sw));
            *(bf16x8*)(out + gbase + qq * 8) = vv;
        }
    }
}

// ---------------- Kernel 3: per-channel triangle GEMM ----------------
// xT[c][i*512+j] = sum_k aT[c][i*512+k] * bT[c][j*512+k]
__global__ __launch_bounds__(256) void k_tri(const u16* __restrict__ aT,
                                             const u16* __restrict__ bT,
                                             u16* __restrict__ xT) {
    __shared__ u16 At[128 * 32];  // [128 rows][32 k] bf16, linear
    __shared__ u16 Bt[128 * 32];
    int tid = threadIdx.x;
    int w = tid >> 6, lane = tid & 63;
    int c  = blockIdx.y;
    int ti = blockIdx.x >> 2, tj = blockIdx.x & 3;
    const char* abase = (const char*)(aT + (long)c * MM) + (long)(ti * 128) * 1024;
    const char* bbase = (const char*)(bT + (long)c * MM) + (long)(tj * 128) * 1024;
    int wm = w >> 1, wn = w & 1;
    int row4 = tid >> 2;          // 0..63
    int ko   = (tid & 3) * 16;    // byte offset within 64B k-row

    f32x4 acc[4][4];
    #pragma unroll
    for (int a = 0; a < 4; ++a)
        #pragma unroll
        for (int bq = 0; bq < 4; ++bq) acc[a][bq] = {0.f,0.f,0.f,0.f};

    for (int ks = 0; ks < 16; ++ks) {
        int kb = ks * 64;  // byte offset in k
        gl_lds16(abase + (long)row4 * 1024 + kb + ko,        (char*)At + w * 1024);
        gl_lds16(abase + (long)(64 + row4) * 1024 + kb + ko, (char*)At + 4096 + w * 1024);
        gl_lds16(bbase + (long)row4 * 1024 + kb + ko,        (char*)Bt + w * 1024);
        gl_lds16(bbase + (long)(64 + row4) * 1024 + kb + ko, (char*)Bt + 4096 + w * 1024);
        __syncthreads();

        bf16x8 af[4];
        #pragma unroll
        for (int mt = 0; mt < 4; ++mt) {
            int rowa = wm * 64 + mt * 16 + (lane & 15);
            af[mt] = *(const bf16x8*)((const char*)At + rowa * 64 + (lane >> 4) * 16);
        }
        #pragma unroll
        for (int nt = 0; nt < 4; ++nt) {
            int rowb = wn * 64 + nt * 16 + (lane & 15);
            bf16x8 bf = *(const bf16x8*)((const char*)Bt + rowb * 64 + (lane >> 4) * 16);
            #pragma unroll
            for (int mt = 0; mt < 4; ++mt)
                acc[mt][nt] = __builtin_amdgcn_mfma_f32_16x16x32_bf16(af[mt], bf, acc[mt][nt], 0, 0, 0);
        }
        __syncthreads();
    }

    u16* xbase = xT + (long)c * MM;
    int gi0 = ti * 128 + wm * 64;
    int gj0 = tj * 128 + wn * 64 + (lane & 15);
    #pragma unroll
    for (int mt = 0; mt < 4; ++mt)
        #pragma unroll
        for (int nt = 0; nt < 4; ++nt)
            #pragma unroll
            for (int j = 0; j < 4; ++j) {
                long gi = gi0 + mt * 16 + (lane >> 4) * 4 + j;
                xbase[gi * NN + gj0 + nt * 16] = f2bf(acc[mt][nt][j]);
            }
}

// ---------------- Kernel 4: LN(x) @ w_z^T + b_z, * g ----------------
__global__ __launch_bounds__(256) void k_out(const u16* __restrict__ xT,
                                             const float* __restrict__ lng,
                                             const float* __restrict__ lnb,
                                             const float* __restrict__ Wz,
                                             const float* __restrict__ Bz,
                                             const u16* __restrict__ gB,
                                             float* __restrict__ outp) {
    __shared__ u16 wzs[16384];   // 32KB, swizzled [n][k]
    __shared__ u16 xl[8192];     // 16KB, swizzled [64 m][128 c]
    int tid = threadIdx.x;
    int w = tid >> 6, lane = tid & 63;
    int m0 = blockIdx.x * 64;
    int r = lane & 15, kq = lane >> 4;

    // stage Wz
    {
        int n = tid >> 1, kb = (tid & 1) * 64;
        int sw = (n & 7) << 4;
        #pragma unroll
        for (int q = 0; q < 16; ++q) {
            int k = kb + q * 4;
            f32x4 wv = *(const f32x4*)(Wz + n * CCH + k);
            u32x2 pk;
            pk.x = (unsigned)f2bf(wv.x) | ((unsigned)f2bf(wv.y) << 16);
            pk.y = (unsigned)f2bf(wv.z) | ((unsigned)f2bf(wv.w) << 16);
            *(u32x2*)((char*)wzs + n * 256 + ((2 * k) ^ sw)) = pk;
        }
    }
    // stage + transpose x tile: read xT[c][m0..m0+64), write xl[m][c]
    {
        int c = tid >> 1, half = tid & 1;
        const u16* src = xT + (long)c * MM + m0 + half * 32;
        #pragma unroll
        for (int qq = 0; qq < 4; ++qq) {
            bf16x8 vv = *(const bf16x8*)(src + qq * 8);
            #pragma unroll
            for (int e = 0; e < 8; ++e) {
                int ml = half * 32 + qq * 8 + e;
                *(u16*)((char*)xl + ml * 256 + ((c * 2) ^ ((ml & 7) << 4))) = (u16)vv[e];
            }
        }
    }
    __syncthreads();

    // LayerNorm per row: 4 lanes per row
    {
        int ml = tid >> 2, p = tid & 3;
        int sw = (ml & 7) << 4;
        float s = 0.f, s2 = 0.f;
        bf16x8 xv[4];
        #pragma unroll
        for (int qq = 0; qq < 4; ++qq) {
            xv[qq] = *(const bf16x8*)((const char*)xl + ml * 256 + ((p * 64 + qq * 16) ^ sw));
            #pragma unroll
            for (int e = 0; e < 8; ++e) {
                float f = bf2f((u16)xv[qq][e]);
                s += f; s2 += f * f;
            }
        }
        s  += __shfl_xor(s, 1);  s  += __shfl_xor(s, 2);
        s2 += __shfl_xor(s2, 1); s2 += __shfl_xor(s2, 2);
        float mu  = s * (1.0f / CCH);
        float var = s2 * (1.0f / CCH) - mu * mu;
        float rs  = rsqrtf(var + 1e-5f);
        #pragma unroll
        for (int qq = 0; qq < 4; ++qq) {
            unsigned pk[4];
            #pragma unroll
            for (int e = 0; e < 8; ++e) {
                int cidx = p * 32 + qq * 8 + e;
                float f = (bf2f((u16)xv[qq][e]) - mu) * rs * lng[cidx] + lnb[cidx];
                u16 h = f2bf(f);
                if ((e & 1) == 0) pk[e >> 1] = h;
                else pk[e >> 1] |= ((unsigned)h) << 16;
            }
            u32x2 p0; p0.x = pk[0]; p0.y = pk[1];
            u32x2 p1; p1.x = pk[2]; p1.y = pk[3];
            *(u32x2*)((char*)xl + ml * 256 + ((p * 64 + qq * 16) ^ sw))     = p0;
            *(u32x2*)((char*)xl + ml * 256 + (((p * 64 + qq * 16) + 8) ^ sw)) = p1;
        }
    }
    __syncthreads();

    // MFMA: rows w*16..+16, all 128 out channels
    int mlr = w * 16 + r;
    int swm = (mlr & 7) << 4;
    bf16x8 av[4];
    #pragma unroll
    for (int kb = 0; kb < 4; ++kb)
        av[kb] = *(const bf16x8*)((const char*)xl + mlr * 256 + ((kb * 64 + kq * 16) ^ swm));

    f32x4 acc[8];
    #pragma unroll
    for (int nt = 0; nt < 8; ++nt) acc[nt] = {0.f,0.f,0.f,0.f};
    #pragma unroll
    for (int nt = 0; nt < 8; ++nt) {
        int nrow = nt * 16 + r;
        int rb = nrow * 256, sw = (nrow & 7) << 4;
        #pragma unroll
        for (int kb = 0; kb < 4; ++kb) {
            bf16x8 bf = *(const bf16x8*)((const char*)wzs + rb + ((kb * 64 + kq * 16) ^ sw));
            acc[nt] = __builtin_amdgcn_mfma_f32_16x16x32_bf16(av[kb], bf, acc[nt], 0, 0, 0);
        }
    }
    #pragma unroll
    for (int nt = 0; nt < 8; ++nt) {
        int cc = nt * 16 + r;
        float bz = Bz[cc];
        #pragma unroll
        for (int j = 0; j < 4; ++j) {
            long m = (long)m0 + w * 16 + kq * 4 + j;
            float gv = bf2f(gB[m * CCH + cc]);
            outp[m * CCH + cc] = (acc[nt][j] + bz) * gv;
        }
    }
}

extern "C" void kernel_launch(void* const* d_in, const int* in_sizes, int n_in,
                              void* d_out, int out_size, void* d_ws, size_t ws_size,
                              hipStream_t stream) {
    const float* z       = (const float*)d_in[0];
    const float* mask    = (const float*)d_in[1];
    const float* ln_in_g = (const float*)d_in[2];
    const float* ln_in_b = (const float*)d_in[3];
    const float* w_ag    = (const float*)d_in[4];
    const float* b_ag    = (const float*)d_in[5];
    const float* w_ap    = (const float*)d_in[6];
    const float* b_ap    = (const float*)d_in[7];
    const float* w_bg    = (const float*)d_in[8];
    const float* b_bg    = (const float*)d_in[9];
    const float* w_bp    = (const float*)d_in[10];
    const float* b_bp    = (const float*)d_in[11];
    const float* w_g     = (const float*)d_in[12];
    const float* b_g     = (const float*)d_in[13];
    const float* w_z     = (const float*)d_in[14];
    const float* b_z     = (const float*)d_in[15];
    const float* ln_o_g  = (const float*)d_in[16];
    const float* ln_o_b  = (const float*)d_in[17];
    float* out = (float*)d_out;

    char* ws = (char*)d_ws;
    const size_t SL = (size_t)MM * CCH * 2;  // 67108864
    u16* zn = (u16*)ws;              // slot 0: zn, later reused as xT
    u16* aT = (u16*)(ws + SL);
    u16* bT = (u16*)(ws + 2 * SL);
    u16* gB = (u16*)(ws + 3 * SL);
    u16* xT = zn;                    // zn dead after k_proj<1>

    k_ln_in<<<MM / 4, 256, 0, stream>>>(z, ln_in_g, ln_in_b, zn);
    k_proj<0><<<MM / 64, 256, 0, stream>>>(zn, mask, w_ag, b_ag, w_ap, b_ap, aT);
    k_proj<0><<<MM / 64, 256, 0, stream>>>(zn, mask, w_bg, b_bg, w_bp, b_bp, bT);
    k_proj<1><<<MM / 64, 256, 0, stream>>>(zn, mask, w_g, b_g, nullptr, nullptr, gB);
    k_tri<<<dim3(16, 128), 256, 0, stream>>>(aT, bT, xT);
    k_out<<<MM / 64, 256, 0, stream>>>(xT, ln_o_g, ln_o_b, w_z, b_z, gB, out);
}